// Round 5
// baseline (795.220 us; speedup 1.0000x reference)
//
#include <hip/hip_runtime.h>
#include <hip/hip_bf16.h>
#include <hip/hip_fp8.h>

#define N_NODES 100000
#define N_EDGES 3200000
#define D_IN 512
#define D_HID 256
#define D_OUT 64
#define M_PAD 100096  // 782 * 128

#define NB 782    // row buckets of 128 rows (row >> 7)
#define EPB 8192  // edges per binning block
#define NBLK_BIN ((N_EDGES + EPB - 1) / EPB)  // 391

typedef __attribute__((ext_vector_type(8))) short bf16x8;
typedef __attribute__((ext_vector_type(4))) float f32x4;

__device__ __forceinline__ unsigned short f2bf(float f) {
    __hip_bfloat16 h = __float2bfloat16(f);
    return *reinterpret_cast<unsigned short*>(&h);
}
__device__ __forceinline__ float f8f(unsigned int byte) {  // fp8 e4m3 -> f32 (HW cvt on gfx950)
    __hip_fp8_e4m3 t;
    t.__x = (__hip_fp8_storage_t)byte;
    return (float)t;
}

// ---------------- small casts ----------------

__global__ void cast_w1t_kernel(const float* __restrict__ w1, __hip_bfloat16* __restrict__ w1t) {
    int i = blockIdx.x * 256 + threadIdx.x;
    if (i >= D_IN * D_HID) return;
    int k = i / D_HID, n = i % D_HID;
    w1t[n * D_IN + k] = __float2bfloat16(w1[i]);
}

__global__ void cast_w2t_kernel(const float* __restrict__ w2, __hip_bfloat16* __restrict__ w2t) {
    int i = blockIdx.x * 256 + threadIdx.x;
    if (i >= D_HID * D_OUT) return;
    int k = i / D_OUT, n = i % D_OUT;
    w2t[n * D_HID + k] = __float2bfloat16(w2[i]);
}

// ---------------- CSR build (two-phase binned) ----------------

__global__ __launch_bounds__(256) void hist_bucket_kernel(const int* __restrict__ row,
                                                          int* __restrict__ gcnt) {
    __shared__ int cnt[NB];
    for (int i = threadIdx.x; i < NB; i += 256) cnt[i] = 0;
    __syncthreads();
    int base = blockIdx.x * EPB;
    for (int i = threadIdx.x; i < EPB; i += 256) {
        int e = base + i;
        if (e < N_EDGES) atomicAdd(&cnt[row[e] >> 7], 1);
    }
    __syncthreads();
    for (int i = threadIdx.x; i < NB; i += 256) {
        int c = cnt[i];
        if (c) atomicAdd(&gcnt[i], c);
    }
}

__global__ void scan_nb_kernel(const int* __restrict__ gcnt, int* __restrict__ boff,
                               int* __restrict__ gcur, int* __restrict__ offsets) {
    __shared__ int smem[1024];
    int t = threadIdx.x;
    int v = (t < NB) ? gcnt[t] : 0;
    smem[t] = v;
    __syncthreads();
    for (int off = 1; off < 1024; off <<= 1) {
        int u = (t >= off) ? smem[t - off] : 0;
        __syncthreads();
        smem[t] += u;
        __syncthreads();
    }
    int excl = smem[t] - v;
    if (t < NB) { boff[t] = excl; gcur[t] = excl; }
    if (t == 1023) boff[NB] = smem[1023];
    if (t == 0) offsets[N_NODES] = N_EDGES;
}

__global__ __launch_bounds__(256) void bin_kernel(const int* __restrict__ row,
                                                  const int* __restrict__ col,
                                                  const float* __restrict__ ew,
                                                  int* __restrict__ gcur,
                                                  int2* __restrict__ bucketed) {
    __shared__ int cnt[NB];
    __shared__ int cur[NB];
    for (int i = threadIdx.x; i < NB; i += 256) cnt[i] = 0;
    __syncthreads();
    int base = blockIdx.x * EPB;
    for (int i = threadIdx.x; i < EPB; i += 256) {
        int e = base + i;
        if (e < N_EDGES) atomicAdd(&cnt[row[e] >> 7], 1);
    }
    __syncthreads();
    for (int i = threadIdx.x; i < NB; i += 256) {
        int c = cnt[i];
        cur[i] = c ? atomicAdd(&gcur[i], c) : 0;
    }
    __syncthreads();
    for (int i = threadIdx.x; i < EPB; i += 256) {
        int e = base + i;
        if (e < N_EDGES) {
            int r = row[e];
            int b = r >> 7;
            int pos = atomicAdd(&cur[b], 1);
            bucketed[pos] = make_int2((col[e] << 7) | (r & 127), __float_as_int(ew[e]));
        }
    }
}

__global__ __launch_bounds__(256) void csr_kernel(const int2* __restrict__ bucketed,
                                                  const int* __restrict__ boff,
                                                  int* __restrict__ offsets,
                                                  int2* __restrict__ edges) {
    __shared__ int rcnt[128];
    __shared__ int sc[128];
    __shared__ int rcur[128];
    int b = blockIdx.x;
    int t = threadIdx.x;
    int s = boff[b], e2 = boff[b + 1];
    if (t < 128) rcnt[t] = 0;
    __syncthreads();
    for (int i = s + t; i < e2; i += 256) atomicAdd(&rcnt[bucketed[i].x & 127], 1);
    __syncthreads();
    if (t < 128) sc[t] = rcnt[t];
    __syncthreads();
    for (int off = 1; off < 128; off <<= 1) {
        int u = 0;
        if (t < 128 && t >= off) u = sc[t - off];
        __syncthreads();
        if (t < 128) sc[t] += u;
        __syncthreads();
    }
    if (t < 128) {
        int excl = sc[t] - rcnt[t];
        rcur[t] = excl;
        int rglob = b * 128 + t;
        if (rglob < N_NODES) offsets[rglob] = s + excl;
    }
    __syncthreads();
    for (int i = s + t; i < e2; i += 256) {
        int2 p = bucketed[i];
        int r = p.x & 127;
        int pos = atomicAdd(&rcur[r], 1);
        edges[s + pos] = make_int2(p.x >> 7, p.y);
    }
}

// ---------------- MFMA GEMM (register-prefetch pipelined) ----------------
// C[M x N] = A[M x K] * Bt[N x K]^T. A either bf16 or fp32 (cast at LDS-write time).
// OUT_MODE: 0 = fp32, 1 = bf16, 2 = fp8 e4m3.
// K-loop: tile k+1's global loads are issued BEFORE tile k's MFMA compute and only
// consumed (cvt + ds_write) at the top of the next iteration -> HBM latency hidden.

template <int BN, int WROWS, int WCOLS, int MT, int NT, bool A_F32, int OUT_MODE>
__global__ __launch_bounds__(256) void gemm_bf16_kernel(
    const void* __restrict__ Av, const __hip_bfloat16* __restrict__ Bt,
    void* __restrict__ Cv, int K, int Mvalid, int Nld) {
    constexpr int BM = 128;
    constexpr int BK = 32;
    constexpr int LDT = BK + 8;
    __shared__ __align__(16) __hip_bfloat16 As[BM][LDT];
    __shared__ __align__(16) __hip_bfloat16 Bs[BN][LDT];

    const int tid = threadIdx.x;
    const int m0 = blockIdx.x * BM;
    const int n0 = blockIdx.y * BN;
    const int w = tid >> 6, lane = tid & 63;
    const int wr = w % WROWS, wc = w / WROWS;
    const int mbase = wr * MT * 16, nbase = wc * NT * 16;
    const int quad = lane >> 4, l16 = lane & 15;

    f32x4 acc[MT][NT] = {};

    constexpr int ACH = (BM * BK) / (256 * 8);
    constexpr int BCH = (BN * BK) / (256 * 8);

    float4 a0[ACH], a1[ACH];  // fp32 A staging regs (A_F32 path)
    uint4 ar[ACH];            // bf16 A staging regs
    uint4 br[BCH];            // B staging regs

    auto load_tile = [&](int k0) {
#pragma unroll
        for (int c = 0; c < ACH; ++c) {
            int idx = (tid + c * 256) * 8;
            int r = idx / BK, kk = idx % BK;
            if constexpr (A_F32) {
                int grow = m0 + r;
                if (grow < Mvalid) {
                    const float* ap = (const float*)Av + (size_t)grow * K + k0 + kk;
                    a0[c] = *reinterpret_cast<const float4*>(ap);
                    a1[c] = *reinterpret_cast<const float4*>(ap + 4);
                } else {
                    a0[c] = float4{0.f, 0.f, 0.f, 0.f};
                    a1[c] = float4{0.f, 0.f, 0.f, 0.f};
                }
            } else {
                ar[c] = *reinterpret_cast<const uint4*>(
                    (const __hip_bfloat16*)Av + (size_t)(m0 + r) * K + k0 + kk);
            }
        }
#pragma unroll
        for (int c = 0; c < BCH; ++c) {
            int idx = (tid + c * 256) * 8;
            int r = idx / BK, kk = idx % BK;
            br[c] = *reinterpret_cast<const uint4*>(&Bt[(size_t)(n0 + r) * K + k0 + kk]);
        }
    };

    auto store_tile = [&]() {
#pragma unroll
        for (int c = 0; c < ACH; ++c) {
            int idx = (tid + c * 256) * 8;
            int r = idx / BK, kk = idx % BK;
            if constexpr (A_F32) {
                uint4 o;
                o.x = (unsigned)f2bf(a0[c].x) | ((unsigned)f2bf(a0[c].y) << 16);
                o.y = (unsigned)f2bf(a0[c].z) | ((unsigned)f2bf(a0[c].w) << 16);
                o.z = (unsigned)f2bf(a1[c].x) | ((unsigned)f2bf(a1[c].y) << 16);
                o.w = (unsigned)f2bf(a1[c].z) | ((unsigned)f2bf(a1[c].w) << 16);
                *reinterpret_cast<uint4*>(&As[r][kk]) = o;
            } else {
                *reinterpret_cast<uint4*>(&As[r][kk]) = ar[c];
            }
        }
#pragma unroll
        for (int c = 0; c < BCH; ++c) {
            int idx = (tid + c * 256) * 8;
            int r = idx / BK, kk = idx % BK;
            *reinterpret_cast<uint4*>(&Bs[r][kk]) = br[c];
        }
    };

    load_tile(0);
    const int NK = K / BK;
    for (int it = 0; it < NK; ++it) {
        if (it > 0) __syncthreads();  // previous compute done before LDS overwrite
        store_tile();
        if (it + 1 < NK) load_tile((it + 1) * BK);  // in flight across compute
        __syncthreads();

        bf16x8 af[MT], bfr[NT];
#pragma unroll
        for (int mt = 0; mt < MT; ++mt)
            af[mt] = *reinterpret_cast<bf16x8*>(&As[mbase + mt * 16 + l16][quad * 8]);
#pragma unroll
        for (int nt = 0; nt < NT; ++nt)
            bfr[nt] = *reinterpret_cast<bf16x8*>(&Bs[nbase + nt * 16 + l16][quad * 8]);
#pragma unroll
        for (int mt = 0; mt < MT; ++mt)
#pragma unroll
            for (int nt = 0; nt < NT; ++nt)
                acc[mt][nt] = __builtin_amdgcn_mfma_f32_16x16x32_bf16(af[mt], bfr[nt],
                                                                      acc[mt][nt], 0, 0, 0);
    }

#pragma unroll
    for (int mt = 0; mt < MT; ++mt)
#pragma unroll
        for (int nt = 0; nt < NT; ++nt)
#pragma unroll
            for (int r = 0; r < 4; ++r) {
                int rowi = m0 + mbase + mt * 16 + quad * 4 + r;
                int coli = n0 + nbase + nt * 16 + l16;
                if (rowi < Mvalid) {
                    if constexpr (OUT_MODE == 0) {
                        ((float*)Cv)[(size_t)rowi * Nld + coli] = acc[mt][nt][r];
                    } else if constexpr (OUT_MODE == 1) {
                        ((__hip_bfloat16*)Cv)[(size_t)rowi * Nld + coli] =
                            __float2bfloat16(acc[mt][nt][r]);
                    } else {
                        __hip_fp8_e4m3 q(acc[mt][nt][r]);
                        ((unsigned char*)Cv)[(size_t)rowi * Nld + coli] = q.__x;
                    }
                }
            }
}

// ---------------- aggregation ----------------

// layer 1: hb = relu(agg(sup1 fp8) + b1) -> bf16; zero-fills pad rows. One wave per node.
__global__ __launch_bounds__(256) void agg1_kernel(
    const unsigned int* __restrict__ sup,  // fp8 [N_NODES][256] as uint[N_NODES][64]
    const int* __restrict__ offsets, const int2* __restrict__ edges,
    const float* __restrict__ b1, __hip_bfloat16* __restrict__ hb) {
    int n = blockIdx.x * 4 + (threadIdx.x >> 6);
    int lane = threadIdx.x & 63;
    if (n >= M_PAD) return;
    if (n >= N_NODES) {
        *reinterpret_cast<ushort4*>(&hb[(size_t)n * D_HID + lane * 4]) = ushort4{0, 0, 0, 0};
        return;
    }
    int s = offsets[n], e2 = offsets[n + 1];
    float a0 = 0.f, a1 = 0.f, a2 = 0.f, a3 = 0.f;
    int e = s;
    for (; e + 8 <= e2; e += 8) {
        int2 m[8];
        unsigned int v[8];
#pragma unroll
        for (int i = 0; i < 8; ++i) m[i] = edges[e + i];
#pragma unroll
        for (int i = 0; i < 8; ++i) v[i] = sup[(size_t)m[i].x * 64 + lane];
#pragma unroll
        for (int i = 0; i < 8; ++i) {
            float wv = __int_as_float(m[i].y);
            a0 += wv * f8f(v[i] & 0xff);
            a1 += wv * f8f((v[i] >> 8) & 0xff);
            a2 += wv * f8f((v[i] >> 16) & 0xff);
            a3 += wv * f8f(v[i] >> 24);
        }
    }
    for (; e < e2; ++e) {
        int2 m = edges[e];
        unsigned int v = sup[(size_t)m.x * 64 + lane];
        float wv = __int_as_float(m.y);
        a0 += wv * f8f(v & 0xff);
        a1 += wv * f8f((v >> 8) & 0xff);
        a2 += wv * f8f((v >> 16) & 0xff);
        a3 += wv * f8f(v >> 24);
    }
    float4 bb = reinterpret_cast<const float4*>(b1)[lane];
    ushort4 o;
    o.x = f2bf(fmaxf(a0 + bb.x, 0.f));
    o.y = f2bf(fmaxf(a1 + bb.y, 0.f));
    o.z = f2bf(fmaxf(a2 + bb.z, 0.f));
    o.w = f2bf(fmaxf(a3 + bb.w, 0.f));
    *reinterpret_cast<ushort4*>(&hb[(size_t)n * D_HID + lane * 4]) = o;
}

// layer 2: agg(sup2 bf16) + b2, log_softmax over 64 dims. One wave per node.
__global__ __launch_bounds__(256) void agg2_softmax_kernel(
    const unsigned short* __restrict__ sup2, const int* __restrict__ offsets,
    const int2* __restrict__ edges, const float* __restrict__ b2, float* __restrict__ out) {
    int n = blockIdx.x * 4 + (threadIdx.x >> 6);
    int j = threadIdx.x & 63;
    if (n >= N_NODES) return;
    int s = offsets[n], e2 = offsets[n + 1];
    float acc = 0.f;
    int e = s;
    for (; e + 4 <= e2; e += 4) {
        int2 m0 = edges[e], m1 = edges[e + 1], m2 = edges[e + 2], m3 = edges[e + 3];
        float v0 = __uint_as_float((unsigned)sup2[(size_t)m0.x * D_OUT + j] << 16);
        float v1 = __uint_as_float((unsigned)sup2[(size_t)m1.x * D_OUT + j] << 16);
        float v2 = __uint_as_float((unsigned)sup2[(size_t)m2.x * D_OUT + j] << 16);
        float v3 = __uint_as_float((unsigned)sup2[(size_t)m3.x * D_OUT + j] << 16);
        acc += __int_as_float(m0.y) * v0;
        acc += __int_as_float(m1.y) * v1;
        acc += __int_as_float(m2.y) * v2;
        acc += __int_as_float(m3.y) * v3;
    }
    for (; e < e2; ++e) {
        int2 m = edges[e];
        acc += __int_as_float(m.y) * __uint_as_float((unsigned)sup2[(size_t)m.x * D_OUT + j] << 16);
    }
    acc += b2[j];
    float m = acc;
#pragma unroll
    for (int o = 32; o > 0; o >>= 1) m = fmaxf(m, __shfl_xor(m, o, 64));
    float ex = __expf(acc - m);
    float ssum = ex;
#pragma unroll
    for (int o = 32; o > 0; o >>= 1) ssum += __shfl_xor(ssum, o, 64);
    out[(size_t)n * D_OUT + j] = acc - m - __logf(ssum);
}

// ---------------- launch ----------------

extern "C" void kernel_launch(void* const* d_in, const int* in_sizes, int n_in,
                              void* d_out, int out_size, void* d_ws, size_t ws_size,
                              hipStream_t stream) {
    const float* x  = (const float*)d_in[0];
    const int* row  = (const int*)d_in[1];
    const int* col  = (const int*)d_in[2];
    const float* ew = (const float*)d_in[3];
    const float* w1 = (const float*)d_in[4];
    const float* b1 = (const float*)d_in[5];
    const float* w2 = (const float*)d_in[6];
    const float* b2 = (const float*)d_in[7];
    float* out = (float*)d_out;

    char* ws = (char*)d_ws;
    size_t off = 0;
    auto alloc = [&](size_t bytes) -> void* {
        void* p = ws + off;
        off = (off + bytes + 255) & ~(size_t)255;
        return p;
    };

    __hip_bfloat16* w1t  = (__hip_bfloat16*)alloc((size_t)D_HID * D_IN * 2);
    __hip_bfloat16* w2t  = (__hip_bfloat16*)alloc((size_t)D_OUT * D_HID * 2);
    unsigned char* sup1  = (unsigned char*)alloc((size_t)N_NODES * D_HID);      // fp8, 25.6 MB
    __hip_bfloat16* hb   = (__hip_bfloat16*)alloc((size_t)M_PAD * D_HID * 2);   // 51.2 MB
    unsigned short* sup2 = (unsigned short*)alloc((size_t)N_NODES * D_OUT * 2); // bf16, 12.8 MB
    int* offsets         = (int*)alloc((size_t)(N_NODES + 1) * 4);
    int* gcnt            = (int*)alloc((size_t)NB * 4);
    int* boff            = (int*)alloc((size_t)(NB + 1) * 4);
    int* gcur            = (int*)alloc((size_t)NB * 4);
    int2* edges          = (int2*)alloc((size_t)N_EDGES * 8);                   // 25.6 MB
    int2* bucketed       = (int2*)alloc((size_t)N_EDGES * 8);                   // 25.6 MB

    // ---- CSR build ----
    hipMemsetAsync(gcnt, 0, (size_t)NB * 4, stream);
    hist_bucket_kernel<<<NBLK_BIN, 256, 0, stream>>>(row, gcnt);
    scan_nb_kernel<<<1, 1024, 0, stream>>>(gcnt, boff, gcur, offsets);
    bin_kernel<<<NBLK_BIN, 256, 0, stream>>>(row, col, ew, gcur, bucketed);
    csr_kernel<<<NB, 256, 0, stream>>>(bucketed, boff, offsets, edges);

    // ---- weight casts ----
    cast_w1t_kernel<<<(D_IN * D_HID + 255) / 256, 256, 0, stream>>>(w1, w1t);
    cast_w2t_kernel<<<(D_HID * D_OUT + 255) / 256, 256, 0, stream>>>(w2, w2t);

    // ---- layer 1: sup1(fp8) = bf16(x) @ w1t^T ; hb = relu(agg + b1) ----
    gemm_bf16_kernel<128, 2, 2, 4, 4, true, 2><<<dim3(M_PAD / 128, D_HID / 128), 256, 0, stream>>>(
        x, w1t, sup1, D_IN, N_NODES, D_HID);
    agg1_kernel<<<M_PAD / 4, 256, 0, stream>>>((const unsigned int*)sup1, offsets, edges, b1, hb);

    // ---- layer 2: sup2(bf16) = hb @ w2t^T ; out = log_softmax(agg + b2) ----
    gemm_bf16_kernel<64, 4, 1, 2, 4, false, 1><<<dim3(M_PAD / 128, 1), 256, 0, stream>>>(
        hb, w2t, sup2, D_HID, N_NODES, D_OUT);
    agg2_softmax_kernel<<<(N_NODES + 3) / 4, 256, 0, stream>>>(sup2, offsets, edges, b2, out);
}